// Round 7
// baseline (144.031 us; speedup 1.0000x reference)
//
#include <hip/hip_runtime.h>
#include <hip/hip_bf16.h>
#include <stdint.h>

// Problem constants (fixed by reference)
#define N_IMG   16
#define C_IN    256
#define H_IN    32
#define W_IN    32
#define OH      30
#define OW      30
#define K_SEL   1152                   // C*KH*KW/2
#define OUTC    512
#define RY_TOT  (N_IMG * OH)           // 480 (n,y) rows
#define M_HAT   (RY_TOT * 32)          // 15360 = padded M (ow 30 -> 32)
#define X_ELEMS (N_IMG * C_IN * H_IN * W_IN)   // 4194304
#define OUT_SP  (OH * OW)              // 900
#define CHW     (C_IN * H_IN * W_IN)   // 262144

#define TO      128                    // o-tile
#define TM      64                     // m-tile
#define NMT     (M_HAT / TM)           // 240
#define NOT     (OUTC / TO)            // 4
#define KITER   (K_SEL / 32)           // 36

typedef float f32x4  __attribute__((ext_vector_type(4)));
typedef short bf16x8 __attribute__((ext_vector_type(8)));   // 8 bf16 = 4 VGPRs

__device__ __forceinline__ unsigned short f2bf(float f) {   // fp32 -> bf16 RNE
    unsigned int u = __float_as_uint(f);
    u += 0x7FFFu + ((u >> 16) & 1u);
    return (unsigned short)(u >> 16);
}

// ---------------------------------------------------------------------------
// Prep: koff decode + coalesced LDS-tile transpose w(K_SEL x OUTC fp32) ->
// wT(OUTC x K_SEL bf16). Grid (36 s-tiles, 16 o-tiles) x 256 thr.
// ---------------------------------------------------------------------------
__global__ void prep_kernel(const int* __restrict__ idx, const float* __restrict__ w,
                            int* __restrict__ koff, unsigned short* __restrict__ wT) {
    __shared__ float tile[32][33];                 // +1 pad: phase1 conflict-free
    const int bx = blockIdx.x, by = blockIdx.y, t = threadIdx.x;

    if (by == 0) {                                 // fold koff decode into first row
        int k = bx * 256 + t;
        if (k < K_SEL) {
            int v = idx[k];
            int c = v / 9, rem = v - c * 9;
            int i = rem / 3, j = rem - i * 3;
            koff[k] = c * (H_IN * W_IN) + i * W_IN + j;
        }
    }
    const int s0 = bx * 32, o0 = by * 32;
    const int oc = t & 31, sg = t >> 5;
#pragma unroll
    for (int i = 0; i < 4; ++i) {                  // coalesced 128B reads along o
        int sl = sg * 4 + i;
        tile[sl][oc] = w[(s0 + sl) * OUTC + o0 + oc];
    }
    __syncthreads();
    const int ol = t >> 3, sq = t & 7;             // write along s: coalesced
    unsigned int u0 = (unsigned int)f2bf(tile[sq * 4 + 0][ol]) |
                      ((unsigned int)f2bf(tile[sq * 4 + 1][ol]) << 16);
    unsigned int u1 = (unsigned int)f2bf(tile[sq * 4 + 2][ol]) |
                      ((unsigned int)f2bf(tile[sq * 4 + 3][ol]) << 16);
    uint2 pk; pk.x = u0; pk.y = u1;
    *reinterpret_cast<uint2*>(&wT[(size_t)(o0 + ol) * K_SEL + s0 + sq * 4]) = pk;
}

// ---------------------------------------------------------------------------
// Fused GEMM, NO LDS operands, NO K-loop barriers.
// R6 post-mortem: LDS round-trip was the bottleneck (4.42M bank-conflict
// cycles; gl_lds16 forbids row padding -> 8-way conflicted ds_read_b128) plus
// barrier-convoy drains. Here every lane loads its own MFMA fragments:
//   A: dwordx4 straight from wT (bf16, L2-resident, 16 rows x 64B / inst)
//   B: 32 x-floats (16-lane coalesced 64B segments, L1-hot) -> cvt-pack
// Register pipeline 1 iter deep; waves free-run (no convoy).
// o-siblings bid / bid+240 (240%8==0 -> same XCD) share the x stream in L2.
// ---------------------------------------------------------------------------
__global__ __launch_bounds__(256, 4)
void gemm_kernel(const unsigned short* __restrict__ wT, const float* __restrict__ x,
                 const int* __restrict__ koff, float* __restrict__ out) {
    __shared__ __align__(16) int koS[K_SEL];       // broadcast reads: conflict-free

    const int t    = threadIdx.x;
    const int wave = t >> 6;
    const int lane = t & 63;
    const int quad = lane >> 4;
    const int lo   = lane & 15;

    const int bid = blockIdx.x;
    const int mt  = bid % NMT;
    const int ot  = bid / NMT;
    const int oBase = ot * TO;
    const int mBase = mt * TM;

    for (int i = t; i < K_SEL; i += 256) koS[i] = koff[i];

    // Per-lane B geometry: for frag ns, m = mBase + ns*16 + lo.
    // Clamp padded xw (30,31) to 29 HERE -> no per-load clamp in hot loop;
    // garbage values masked at the epilogue store.
    int bxy[4];
#pragma unroll
    for (int ns = 0; ns < 4; ++ns) {
        int m  = mBase + ns * 16 + lo;
        int xw = m & 31;
        int ryg = m >> 5;
        int n = ryg / 30, y = ryg - n * 30;
        bxy[ns] = n * CHW + y * W_IN + min(xw, OW - 1);
    }

    // Per-lane A row pointers (element j of frag ms = wT[row_ms][k0+quad*8+j])
    const unsigned short* ap0 = wT + (size_t)(oBase + wave * 32 + lo) * K_SEL + quad * 8;
    const unsigned short* ap1 = ap0 + (size_t)16 * K_SEL;

    __syncthreads();                               // koS ready (only barrier)

    f32x4  acc[2][4] = {};
    bf16x8 anxt[2];
    float  bnxt[4][8];

    // ---- prologue: load kt=0 operands ----
    {
        int4 kA = *(const int4*)&koS[quad * 8];
        int4 kB = *(const int4*)&koS[quad * 8 + 4];
        anxt[0] = *(const bf16x8*)(ap0);
        anxt[1] = *(const bf16x8*)(ap1);
#pragma unroll
        for (int ns = 0; ns < 4; ++ns) {
            bnxt[ns][0] = x[bxy[ns] + kA.x];
            bnxt[ns][1] = x[bxy[ns] + kA.y];
            bnxt[ns][2] = x[bxy[ns] + kA.z];
            bnxt[ns][3] = x[bxy[ns] + kA.w];
            bnxt[ns][4] = x[bxy[ns] + kB.x];
            bnxt[ns][5] = x[bxy[ns] + kB.y];
            bnxt[ns][6] = x[bxy[ns] + kB.z];
            bnxt[ns][7] = x[bxy[ns] + kB.w];
        }
    }

    for (int kt = 0; kt < KITER; ++kt) {
        // 1) consume bnxt -> bf16 frags (frees bnxt for next loads)
        bf16x8 bf[4];
#pragma unroll
        for (int ns = 0; ns < 4; ++ns) {
            unsigned int u[4];
            __hip_bfloat162 h0 = __float22bfloat162_rn({bnxt[ns][0], bnxt[ns][1]});
            __hip_bfloat162 h1 = __float22bfloat162_rn({bnxt[ns][2], bnxt[ns][3]});
            __hip_bfloat162 h2 = __float22bfloat162_rn({bnxt[ns][4], bnxt[ns][5]});
            __hip_bfloat162 h3 = __float22bfloat162_rn({bnxt[ns][6], bnxt[ns][7]});
            __builtin_memcpy(&u[0], &h0, 4);
            __builtin_memcpy(&u[1], &h1, 4);
            __builtin_memcpy(&u[2], &h2, 4);
            __builtin_memcpy(&u[3], &h3, 4);
            __builtin_memcpy(&bf[ns], u, 16);
        }
        bf16x8 a0 = anxt[0], a1 = anxt[1];

        // 2) issue next iter's loads (latency covered by this iter's MFMA)
        if (kt + 1 < KITER) {
            const int kb = (kt + 1) * 32;
            int4 kA = *(const int4*)&koS[kb + quad * 8];
            int4 kB = *(const int4*)&koS[kb + quad * 8 + 4];
            anxt[0] = *(const bf16x8*)(ap0 + kb);
            anxt[1] = *(const bf16x8*)(ap1 + kb);
#pragma unroll
            for (int ns = 0; ns < 4; ++ns) {
                bnxt[ns][0] = x[bxy[ns] + kA.x];
                bnxt[ns][1] = x[bxy[ns] + kA.y];
                bnxt[ns][2] = x[bxy[ns] + kA.z];
                bnxt[ns][3] = x[bxy[ns] + kA.w];
                bnxt[ns][4] = x[bxy[ns] + kB.x];
                bnxt[ns][5] = x[bxy[ns] + kB.y];
                bnxt[ns][6] = x[bxy[ns] + kB.z];
                bnxt[ns][7] = x[bxy[ns] + kB.w];
            }
        }

        // 3) MFMA
#pragma unroll
        for (int ns = 0; ns < 4; ++ns)
            acc[0][ns] = __builtin_amdgcn_mfma_f32_16x16x32_bf16(a0, bf[ns], acc[0][ns], 0, 0, 0);
#pragma unroll
        for (int ns = 0; ns < 4; ++ns)
            acc[1][ns] = __builtin_amdgcn_mfma_f32_16x16x32_bf16(a1, bf[ns], acc[1][ns], 0, 0, 0);
    }

    // Epilogue (verified mapping): D row = o (quad*4+r), col = m (lane&15).
#pragma unroll
    for (int ns = 0; ns < 4; ++ns) {
        const int mh  = mBase + ns * 16 + lo;
        const int xwe = mh & 31;
        const int ryg = mh >> 5;
        const int n = ryg / 30, y = ryg - n * 30;
        if (xwe < OW) {
            const size_t ob = (size_t)n * (OUTC * OUT_SP) + (size_t)y * OW + xwe;
#pragma unroll
            for (int ms = 0; ms < 2; ++ms) {
                const int o0 = oBase + wave * 32 + ms * 16 + quad * 4;
#pragma unroll
                for (int r = 0; r < 4; ++r)
                    out[ob + (size_t)(o0 + r) * OUT_SP] = acc[ms][ns][r];
            }
        }
    }
}

// ---------------------------------------------------------------------------
extern "C" void kernel_launch(void* const* d_in, const int* in_sizes, int n_in,
                              void* d_out, int out_size, void* d_ws, size_t ws_size,
                              hipStream_t stream) {
    const float* x   = (const float*)d_in[0];
    const float* w   = (const float*)d_in[1];
    const int*   idx = (const int*)d_in[2];
    float*       out = (float*)d_out;

    // ws layout: koff 4608B | wT bf16 1179648B  (~1.2 MB total)
    char* ws = (char*)d_ws;
    int*            koff = (int*)ws;
    unsigned short* wT   = (unsigned short*)(ws + 4608);

    prep_kernel<<<dim3(K_SEL / 32, OUTC / 32), dim3(256), 0, stream>>>(idx, w, koff, wT);
    gemm_kernel<<<dim3(NMT * NOT), dim3(256), 0, stream>>>(wT, x, koff, out);
}

// Round 8
// 134.620 us; speedup vs baseline: 1.0699x; 1.0699x over previous
//
#include <hip/hip_runtime.h>
#include <hip/hip_bf16.h>
#include <stdint.h>

// Problem constants (fixed by reference)
#define N_IMG   16
#define C_IN    256
#define H_IN    32
#define W_IN    32
#define OH      30
#define OW      30
#define K_SEL   1152                   // C*KH*KW/2
#define OUTC    512
#define RY_TOT  (N_IMG * OH)           // 480 (n,y) rows
#define M_HAT   (RY_TOT * 32)          // 15360 = padded M (ow 30 -> 32)
#define X_ELEMS (N_IMG * C_IN * H_IN * W_IN)   // 4194304
#define OUT_SP  (OH * OW)              // 900
#define CHW     (C_IN * H_IN * W_IN)   // 262144

#define TO      128                    // o-tile (R3 shape — best measured)
#define TM      64                     // m-tile = 2 ry rows x 32 xw
#define NMT     (M_HAT / TM)           // 240
#define NOT     (OUTC / TO)            // 4
#define BK      64                     // NEW: 2x k-depth -> half the barriers
#define KIT2    (K_SEL / BK)           // 18
#define BSTR    72                     // Bs row stride (shorts): 144B rows, 16B-aligned

typedef float f32x4  __attribute__((ext_vector_type(4)));
typedef short bf16x8 __attribute__((ext_vector_type(8)));   // 8 bf16 = 4 VGPRs

__device__ __forceinline__ unsigned short f2bf(float f) {   // fp32 -> bf16 RNE
    unsigned int u = __float_as_uint(f);
    u += 0x7FFFu + ((u >> 16) & 1u);
    return (unsigned short)(u >> 16);
}

// async global->LDS, 16B/lane; LDS dst wave-uniform base, HW adds lane*16.
__device__ __forceinline__ void gl_lds16(const void* g, void* lds) {
    __builtin_amdgcn_global_load_lds(
        (const __attribute__((address_space(1))) unsigned int*)g,
        (__attribute__((address_space(3))) unsigned int*)lds,
        16, 0, 0);
}

// ---------------------------------------------------------------------------
// Prep: koff decode + coalesced LDS-tile transpose w(K_SEL x OUTC fp32) ->
// wT(OUTC x K_SEL bf16), with k XOR-SWIZZLED inside each 64-block by
// (o&7)*8 so that As fragment reads in the GEMM are bank-conflict-free
// (gl_lds16 forbids padding; swizzle is the only conflict fix available).
// ---------------------------------------------------------------------------
__global__ void prep_kernel(const int* __restrict__ idx, const float* __restrict__ w,
                            int* __restrict__ koff, unsigned short* __restrict__ wT) {
    __shared__ float tile[32][33];                 // +1 pad: phase1 conflict-free
    const int bx = blockIdx.x, by = blockIdx.y, t = threadIdx.x;

    if (by == 0) {                                 // fold koff decode into first row
        int k = bx * 256 + t;
        if (k < K_SEL) {
            int v = idx[k];
            int c = v / 9, rem = v - c * 9;
            int i = rem / 3, j = rem - i * 3;
            koff[k] = c * (H_IN * W_IN) + i * W_IN + j;
        }
    }
    const int s0 = bx * 32, o0 = by * 32;
    const int oc = t & 31, sg = t >> 5;
#pragma unroll
    for (int i = 0; i < 4; ++i) {                  // coalesced 128B reads along o
        int sl = sg * 4 + i;
        tile[sl][oc] = w[(s0 + sl) * OUTC + o0 + oc];
    }
    __syncthreads();
    const int ol = t >> 3, sq = t & 7;             // write along s: coalesced
    unsigned int u0 = (unsigned int)f2bf(tile[sq * 4 + 0][ol]) |
                      ((unsigned int)f2bf(tile[sq * 4 + 1][ol]) << 16);
    unsigned int u1 = (unsigned int)f2bf(tile[sq * 4 + 2][ol]) |
                      ((unsigned int)f2bf(tile[sq * 4 + 3][ol]) << 16);
    uint2 pk; pk.x = u0; pk.y = u1;
    const int kk   = s0 + sq * 4;
    const int kswz = (kk & ~63) | ((kk & 63) ^ ((ol & 7) * 8));  // XOR bits 3-5
    *reinterpret_cast<uint2*>(&wT[(size_t)(o0 + ol) * K_SEL + kswz]) = pk;
}

// ---------------------------------------------------------------------------
// Fused GEMM (R3 skeleton, BK=64, swizzled conflict-free LDS).
// out[n,o,y,x] = sum_k wT[o][k] * x[n, koff[k] + y*32 + xw]
// Tile 128o x 64m, 960 blocks. Per iter: stage A (4x gl_lds16, swizzled wT),
// pack prefetched x -> Bs (1x ds_write_b128 per ry), prefetch x(kt+1),
// barrier, 16 MFMA from swizzled frag reads (2-way max = free), barrier.
// 36 barriers total (R3: 72); conflicts ~0 (R3: 4.42M).
// ---------------------------------------------------------------------------
__global__ __launch_bounds__(256, 4)
void gemm_kernel(const unsigned short* __restrict__ wT, const float* __restrict__ x,
                 const int* __restrict__ koff, float* __restrict__ out) {
    __shared__ __align__(16) unsigned short As[TO * BK];    // 16 KB, k-swizzled rows
    __shared__ __align__(16) unsigned short Bs[TM * BSTR];  // 9 KB, stride-72 rows
    __shared__ __align__(16) int koS[K_SEL];

    const int t    = threadIdx.x;
    const int wave = t >> 6;
    const int lane = t & 63;
    const int quad = lane >> 4;
    const int lo   = lane & 15;

    const int bid = blockIdx.x;
    const int mt  = bid % NMT;
    const int ot  = bid / NMT;
    const int oBase = ot * TO;
    const int mBase = mt * TM;

    for (int i = t; i < K_SEL; i += 256) koS[i] = koff[i];

    const int xw = t & 31;                         // spatial lane within ry row
    const int ks = (t >> 5) * 8;                   // this thread's 8 k's within BK

    int bxy[2];
#pragma unroll
    for (int ry = 0; ry < 2; ++ry) {
        int ryg = mt * 2 + ry;
        int n = ryg / 30, y = ryg - n * 30;
        bxy[ry] = n * CHW + y * W_IN + xw;
    }

    // A staging: chunk c covers rows c*32 + wave*8 + (lane>>3), 16B at (lane&7)*8
    const unsigned short* wrowA = wT + (size_t)(oBase + wave * 8 + (lane >> 3)) * K_SEL
                                     + (lane & 7) * 8;
    // swizzled k-offsets for fragment reads (row&7 == lo&7 for all our rows)
    const int kx0 = (quad * 8) ^ ((lo & 7) * 8);
    const int kx1 = (32 + quad * 8) ^ ((lo & 7) * 8);
    const int bwk = ks ^ ((xw & 7) * 8);           // Bs write k-offset (row&7 == xw&7)

    __syncthreads();                               // koS ready

    f32x4 acc[2][4] = {};
    float v[2][2][8];                              // [buf][ry][8k]
    int4  kA, kB;

    // ---- prologue: x for kt=0 ----
    kA = *reinterpret_cast<const int4*>(&koS[ks]);
    kB = *reinterpret_cast<const int4*>(&koS[ks + 4]);
#pragma unroll
    for (int ry = 0; ry < 2; ++ry) {
        v[0][ry][0] = x[bxy[ry] + kA.x];
        v[0][ry][1] = x[bxy[ry] + kA.y];
        v[0][ry][2] = x[bxy[ry] + kA.z];
        v[0][ry][3] = x[bxy[ry] + kA.w];
        v[0][ry][4] = x[bxy[ry] + kB.x];
        v[0][ry][5] = x[bxy[ry] + kB.y];
        v[0][ry][6] = x[bxy[ry] + kB.z];
        v[0][ry][7] = x[bxy[ry] + kB.w];
    }

    for (int kt = 0; kt < KIT2; ++kt) {
        const int p = kt & 1, q = p ^ 1;
        const int kb = kt * BK;
#pragma unroll
        for (int c = 0; c < 4; ++c)                // stage A tile (swizzled source)
            gl_lds16(wrowA + (size_t)c * 32 * K_SEL + kb, &As[(c * 32 + wave * 8) * BK]);

        // commit current B: 8 floats -> 4 bf162 -> one ds_write_b128 per ry
#pragma unroll
        for (int ry = 0; ry < 2; ++ry) {
            __hip_bfloat162 h0 = __float22bfloat162_rn({v[p][ry][0], v[p][ry][1]});
            __hip_bfloat162 h1 = __float22bfloat162_rn({v[p][ry][2], v[p][ry][3]});
            __hip_bfloat162 h2 = __float22bfloat162_rn({v[p][ry][4], v[p][ry][5]});
            __hip_bfloat162 h3 = __float22bfloat162_rn({v[p][ry][6], v[p][ry][7]});
            uint4 pk;
            __builtin_memcpy(&pk.x, &h0, 4);
            __builtin_memcpy(&pk.y, &h1, 4);
            __builtin_memcpy(&pk.z, &h2, 4);
            __builtin_memcpy(&pk.w, &h3, 4);
            *reinterpret_cast<uint4*>(&Bs[(ry * 32 + xw) * BSTR + bwk]) = pk;
        }
        // prefetch next iter's x (latency covered by MFMA section)
        if (kt + 1 < KIT2) {
            kA = *reinterpret_cast<const int4*>(&koS[kb + BK + ks]);
            kB = *reinterpret_cast<const int4*>(&koS[kb + BK + ks + 4]);
#pragma unroll
            for (int ry = 0; ry < 2; ++ry) {
                v[q][ry][0] = x[bxy[ry] + kA.x];
                v[q][ry][1] = x[bxy[ry] + kA.y];
                v[q][ry][2] = x[bxy[ry] + kA.z];
                v[q][ry][3] = x[bxy[ry] + kA.w];
                v[q][ry][4] = x[bxy[ry] + kB.x];
                v[q][ry][5] = x[bxy[ry] + kB.y];
                v[q][ry][6] = x[bxy[ry] + kB.z];
                v[q][ry][7] = x[bxy[ry] + kB.w];
            }
        }
        __syncthreads();                           // As (vmcnt) + Bs (lgkmcnt) visible

#pragma unroll
        for (int g = 0; g < 2; ++g) {              // two k=32 MFMA groups
            const int kx = g ? kx1 : kx0;
            bf16x8 a0 = *(const bf16x8*)&As[(wave * 32 + lo) * BK + kx];
            bf16x8 a1 = *(const bf16x8*)&As[(wave * 32 + 16 + lo) * BK + kx];
            bf16x8 b[4];
#pragma unroll
            for (int ns = 0; ns < 4; ++ns)
                b[ns] = *(const bf16x8*)&Bs[(ns * 16 + lo) * BSTR + kx];
#pragma unroll
            for (int ns = 0; ns < 4; ++ns)
                acc[0][ns] = __builtin_amdgcn_mfma_f32_16x16x32_bf16(a0, b[ns], acc[0][ns], 0, 0, 0);
#pragma unroll
            for (int ns = 0; ns < 4; ++ns)
                acc[1][ns] = __builtin_amdgcn_mfma_f32_16x16x32_bf16(a1, b[ns], acc[1][ns], 0, 0, 0);
        }
        __syncthreads();                           // tiles consumed before next stage
    }

    // Epilogue (verified mapping): D row = o (quad*4+r), col = m (lane&15).
#pragma unroll
    for (int ns = 0; ns < 4; ++ns) {
        const int mh  = mBase + ns * 16 + lo;
        const int xwe = mh & 31;
        const int ryg = mh >> 5;
        const int n = ryg / 30, y = ryg - n * 30;
        if (xwe < OW) {
            const size_t ob = (size_t)n * (OUTC * OUT_SP) + (size_t)y * OW + xwe;
#pragma unroll
            for (int ms = 0; ms < 2; ++ms) {
                const int o0 = oBase + wave * 32 + ms * 16 + quad * 4;
#pragma unroll
                for (int r = 0; r < 4; ++r)
                    out[ob + (size_t)(o0 + r) * OUT_SP] = acc[ms][ns][r];
            }
        }
    }
}

// ---------------------------------------------------------------------------
extern "C" void kernel_launch(void* const* d_in, const int* in_sizes, int n_in,
                              void* d_out, int out_size, void* d_ws, size_t ws_size,
                              hipStream_t stream) {
    const float* x   = (const float*)d_in[0];
    const float* w   = (const float*)d_in[1];
    const int*   idx = (const int*)d_in[2];
    float*       out = (float*)d_out;

    // ws layout: koff 4608B | wT bf16 1179648B  (~1.2 MB total)
    char* ws = (char*)d_ws;
    int*            koff = (int*)ws;
    unsigned short* wT   = (unsigned short*)(ws + 4608);

    prep_kernel<<<dim3(K_SEL / 32, OUTC / 32), dim3(256), 0, stream>>>(idx, w, koff, wT);
    gemm_kernel<<<dim3(NMT * NOT), dim3(256), 0, stream>>>(wT, x, koff, out);
}